// Round 1
// baseline (828.774 us; speedup 1.0000x reference)
//
#include <hip/hip_runtime.h>
#include <stdint.h>

#define BB 4
#define CC 256
#define HH 256
#define WW 256
#define TH 32            // output rows per tile
#define TR 36            // rows incl 2+2 halo
#define NCHUNK 16        // channels per block
#define CODE_BYTES (TR*WW)              // 9216
#define F_OFF CODE_BYTES                // F tile follows code tile in LDS
#define LDS_BYTES (CODE_BYTES + TR*WW*4 + 16)  // +16B slack for +2-col overflow reads

// ---------------- kernel 0: zero accumulators (ws is poisoned 0xAA) ----------------
__global__ void k_init(unsigned int* p) {
    if (threadIdx.x < 8) p[threadIdx.x] = 0;   // 2 doubles (lsum) + 4 uints (counts) = 32B
}

// ---------------- kernel 1: per-pixel code byte: lab | good<<2 | edge<<3 ----------------
__global__ void k_code(const float* __restrict__ cls, const int* __restrict__ gt,
                       unsigned char* __restrict__ code) {
    int i = blockIdx.x * 256 + threadIdx.x;        // [0, B*H*W)
    int w = i & 255, h = (i >> 8) & 255, b = i >> 16;
    int g = gt[i];
    float c0 = cls[((b*2 + 0)*HH + h)*WW + w];
    float c1 = cls[((b*2 + 1)*HH + h)*WW + w];
    int pred = (c1 > c0) ? 1 : 0;                  // jnp.argmax tie -> 0
    int ud = (h < HH-5) ? (gt[i + 5*WW] != g) : 0; // pad at END of axis (matches jnp.pad)
    int lr = (w < WW-5) ? (gt[i + 5] != g) : 0;
    int edge = (ud | lr | (g == -1)) ? 1 : 0;
    int lab = (g == 0) ? 0 : ((g == 1) ? 1 : 2);
    int good = (lab < 2 && pred == g) ? 1 : 0;
    code[i] = (unsigned char)(lab | (good << 2) | (edge << 3));
}

// ---------------- kernel 2: global cal/mse counts per class ----------------
__global__ void k_counts(const unsigned char* __restrict__ code, unsigned int* cnts) {
    int i = blockIdx.x * 256 + threadIdx.x;
    int w = i & 255, h = (i >> 8) & 255, b = i >> 16;
    unsigned char cb = code[i];
    int lab = cb & 3, good = (cb >> 2) & 1, edge = (cb >> 3) & 1;
    int ccls = 0, ccorr = 0;
    if (lab < 2 && edge) {
        for (int dh = -2; dh <= 2; dh++) {
            int hh = h + dh; if ((unsigned)hh >= HH) continue;
            for (int dw = -2; dw <= 2; dw++) {
                if (dh == 0 && dw == 0) continue;
                int ww2 = w + dw; if ((unsigned)ww2 >= WW) continue;
                unsigned char q = code[(b*HH + hh)*WW + ww2];
                if ((q & 3) == lab) { ccls++; ccorr += (q >> 2) & 1; }
            }
        }
    }
    int cal = (lab < 2) && edge && (ccls >= 1);
    int mse = (lab < 2) && edge && good && (ccorr >= 1);
    unsigned long long b0 = __ballot(cal && lab == 0);
    unsigned long long b1 = __ballot(cal && lab == 1);
    unsigned long long b2 = __ballot(mse && lab == 0);
    unsigned long long b3 = __ballot(mse && lab == 1);
    if ((threadIdx.x & 63) == 0) {
        atomicAdd(&cnts[0], (unsigned)__popcll(b0));
        atomicAdd(&cnts[1], (unsigned)__popcll(b1));
        atomicAdd(&cnts[2], (unsigned)__popcll(b2));
        atomicAdd(&cnts[3], (unsigned)__popcll(b3));
    }
}

// ---------------- kernel 3: the heavy pass ----------------
// grid = B * (H/TH) * (C/NCHUNK) = 4*8*16 = 512 blocks, 256 threads (thread t = column t)
__global__ __launch_bounds__(256) void k_loss(const float* __restrict__ F,
                                              const unsigned char* __restrict__ code,
                                              double* __restrict__ lsum) {
    __shared__ __align__(16) unsigned char lds[LDS_BYTES];
    __shared__ float red[8];
    float* Ft = (float*)(lds + F_OFF);
    const int t = threadIdx.x;
    const int bx = blockIdx.x;
    const int chunk = bx & 15, tile = (bx >> 4) & 7, b = bx >> 7;
    const int r0 = tile * TH;
    const int gtop = r0 - 2;

    // ---- stage code tile (zero-fill out-of-image rows) ----
    for (int idx = t; idx < TR*WW/4; idx += 256) {
        int rr = idx >> 6;                  // 64 words per row
        int grow = gtop + rr;
        unsigned int v = 0;
        if ((unsigned)grow < HH)
            v = ((const unsigned int*)code)[(b*HH + grow)*(WW/4) + (idx & 63)];
        ((unsigned int*)lds)[idx] = v;
    }
    __syncthreads();

    // ---- per-thread precompute: hm[36] (5+5 bit masks), w[32], mse/lab bits ----
    unsigned int hm[TR];
    float wq[TH];
    unsigned int msebits = 0, labbits = 0;
    {
        int pr0[5], pr1[5];
        unsigned char cbr[5];
        #pragma unroll
        for (int rr = 0; rr < TR; rr++) {
            unsigned int m = 0;
            unsigned char center = 0;
            #pragma unroll
            for (int j = 0; j < 5; j++) {
                int col = t - 2 + j;
                int colc = min(max(col, 0), WW - 1);
                unsigned char q = lds[rr*WW + colc];
                if ((unsigned)col >= WW) q = 0;
                if (j == 2) center = q;
                int g = (q >> 2) & 1;
                m |= ((unsigned)((((q & 3) == 0) & g))) << j;
                m |= ((unsigned)((((q & 3) == 1) & g))) << (5 + j);
            }
            hm[rr] = m;
            pr0[rr % 5] = __popc(m & 31);
            pr1[rr % 5] = __popc((m >> 5) & 31);
            cbr[rr % 5] = center;
            if (rr >= 4) {
                int ro = rr - 4;                       // output row in [0,32)
                unsigned char cb = cbr[(rr - 2) % 5];  // own code byte at tile row ro+2
                int lab = cb & 3, good = (cb >> 2) & 1, edge = (cb >> 3) & 1;
                int cnt5 = (lab == 1) ? (pr1[0]+pr1[1]+pr1[2]+pr1[3]+pr1[4])
                                      : (pr0[0]+pr0[1]+pr0[2]+pr0[3]+pr0[4]);
                int ccorr = cnt5 - good;               // ring count (exclude center)
                int mse = (lab < 2) && edge && good && (ccorr >= 1);
                wq[ro] = mse ? (1.0f / ((float)ccorr + 1e-5f)) : 0.0f;
                msebits |= ((unsigned)mse) << ro;
                labbits |= ((unsigned)(lab & 1)) << ro;
            }
        }
    }

    // ---- channel loop ----
    float acc0 = 0.f, acc1 = 0.f;
    const int rrbeg = (gtop < 0) ? -gtop : 0;
    const int rrend = (gtop + TR > HH) ? (HH - gtop) : TR;
    #pragma unroll 1
    for (int c = 0; c < NCHUNK; c++) {
        int ch = chunk * NCHUNK + c;
        const float* plane = F + ((size_t)(b*CC + ch)) * (HH*WW);
        // stage F tile: full-width rows => contiguous chunk; stale halo rows are masked out
        {
            const float4* src = (const float4*)(plane + (gtop + rrbeg)*WW);
            float4* dst = (float4*)(Ft + rrbeg*WW);
            int n4 = (rrend - rrbeg) * (WW/4);
            for (int idx = t; idx < n4; idx += 256) dst[idx] = src[idx];
        }
        __syncthreads();
        float R0r[5], R1r[5], fcr[5];
        #pragma unroll
        for (int rr = 0; rr < TR; rr++) {
            const float* fp = Ft + rr*WW + t - 2;   // -2..+2 stays inside lds (code region slack / tail slack)
            float f0 = fp[0], f1 = fp[1], f2 = fp[2], f3 = fp[3], f4 = fp[4];
            unsigned int m = hm[rr];
            float r0 = ((m & 1)  ? f0 : 0.f) + ((m & 2)  ? f1 : 0.f) + ((m & 4)  ? f2 : 0.f)
                     + ((m & 8)  ? f3 : 0.f) + ((m & 16) ? f4 : 0.f);
            float r1 = ((m & (1u<<5)) ? f0 : 0.f) + ((m & (2u<<5)) ? f1 : 0.f) + ((m & (4u<<5)) ? f2 : 0.f)
                     + ((m & (8u<<5)) ? f3 : 0.f) + ((m & (16u<<5)) ? f4 : 0.f);
            R0r[rr % 5] = r0; R1r[rr % 5] = r1; fcr[rr % 5] = f2;
            if (rr >= 4) {
                int ro = rr - 4;
                if ((msebits >> ro) & 1) {
                    float s0 = R0r[0]+R0r[1]+R0r[2]+R0r[3]+R0r[4];
                    float s1 = R1r[0]+R1r[1]+R1r[2]+R1r[3]+R1r[4];
                    int lab = (labbits >> ro) & 1;
                    float fc = fcr[(rr - 2) % 5];
                    float S = (lab ? s1 : s0) - fc;       // ring sum (center has good=1)
                    float d = fc - S * wq[ro];
                    float dd = d * d;
                    if (lab) acc1 += dd; else acc0 += dd;
                }
            }
        }
        __syncthreads();
    }

    // ---- reduce: wave shuffle -> LDS -> double atomics ----
    for (int off = 32; off > 0; off >>= 1) {
        acc0 += __shfl_down(acc0, off, 64);
        acc1 += __shfl_down(acc1, off, 64);
    }
    int wave = t >> 6, lane = t & 63;
    if (lane == 0) { red[wave*2] = acc0; red[wave*2 + 1] = acc1; }
    __syncthreads();
    if (t == 0) {
        float a0 = red[0] + red[2] + red[4] + red[6];
        float a1 = red[1] + red[3] + red[5] + red[7];
        atomicAdd(&lsum[0], (double)a0);
        atomicAdd(&lsum[1], (double)a1);
    }
}

// ---------------- kernel 4: finalize scalar ----------------
__global__ void k_final(const double* __restrict__ lsum,
                        const unsigned int* __restrict__ cnts, float* out) {
    if (threadIdx.x == 0 && blockIdx.x == 0) {
        float total = 0.f, ncls = 0.f;
        for (int c = 0; c < 2; c++) {
            double num = lsum[c];
            unsigned int calc = cnts[c], msec = cnts[2 + c];
            float denom = fmaxf((float)msec * (float)CC, 1.0f);
            float lc = (float)(num / (double)denom);
            if (calc >= 1u && msec >= 1u) { total += lc; ncls += 1.f; }
        }
        out[0] = (ncls == 0.f) ? total : total / fmaxf(ncls, 1.f);
    }
}

extern "C" void kernel_launch(void* const* d_in, const int* in_sizes, int n_in,
                              void* d_out, int out_size, void* d_ws, size_t ws_size,
                              hipStream_t stream) {
    const float* feats = (const float*)d_in[0];        // [4,256,256,256] fp32
    const float* cls   = (const float*)d_in[1];        // [4,2,256,256] fp32
    const int*   gt    = (const int*)d_in[2];          // [4,256,256] int32
    double* lsum = (double*)d_ws;                      // [0,16)
    unsigned int* cnts = (unsigned int*)((char*)d_ws + 16);  // [16,32)
    unsigned char* code = (unsigned char*)d_ws + 64;   // B*H*W bytes
    float* out = (float*)d_out;

    const int npix = BB*HH*WW;
    k_init<<<1, 64, 0, stream>>>((unsigned int*)d_ws);
    k_code<<<npix/256, 256, 0, stream>>>(cls, gt, code);
    k_counts<<<npix/256, 256, 0, stream>>>(code, cnts);
    k_loss<<<BB*(HH/TH)*(CC/NCHUNK), 256, 0, stream>>>(feats, code, lsum);
    k_final<<<1, 64, 0, stream>>>(lsum, cnts, out);
}

// Round 2
// 444.149 us; speedup vs baseline: 1.8660x; 1.8660x over previous
//
#include <hip/hip_runtime.h>
#include <stdint.h>

#define BB 4
#define CC 256
#define HH 256
#define WW 256
#define TH 16                 // output rows per block
#define TR 20                 // rows incl 2+2 halo
#define NCH 8                 // channels per block
#define NTILES (HH/TH)        // 16
#define NCHUNKS (CC/NCH)      // 32

// ---------------- kernel 0: zero accumulators (ws is poisoned 0xAA) ----------------
__global__ void k_init(unsigned int* p) {
    if (threadIdx.x < 8) p[threadIdx.x] = 0;   // 2 doubles (lsum) + 4 uints (counts)
}

// ---------------- kernel 1: per-pixel code byte: lab | good<<2 | edge<<3 ----------------
__global__ void k_code(const float* __restrict__ cls, const int* __restrict__ gt,
                       unsigned char* __restrict__ code) {
    int i = blockIdx.x * 256 + threadIdx.x;        // [0, B*H*W)
    int w = i & 255, h = (i >> 8) & 255;
    int b = i >> 16;
    int g = gt[i];
    float c0 = cls[((b*2 + 0)*HH + h)*WW + w];
    float c1 = cls[((b*2 + 1)*HH + h)*WW + w];
    int pred = (c1 > c0) ? 1 : 0;                  // jnp.argmax tie -> 0
    int ud = (h < HH-5) ? (gt[i + 5*WW] != g) : 0; // pad at END of axis (matches jnp.pad)
    int lr = (w < WW-5) ? (gt[i + 5] != g) : 0;
    int edge = (ud | lr | (g == -1)) ? 1 : 0;
    int lab = (g == 0) ? 0 : ((g == 1) ? 1 : 2);
    int good = (lab < 2 && pred == g) ? 1 : 0;
    code[i] = (unsigned char)(lab | (good << 2) | (edge << 3));
}

__device__ __forceinline__ float f4get(const float4& v, int j) {
    switch (j) { case 0: return v.x; case 1: return v.y; case 2: return v.z; default: return v.w; }
}

// horizontal 5-window sums over 4 cols/lane (cols 4l..4l+3), halo via wave shuffle
__device__ __forceinline__ void hwin_f(const float* vs, float* S, int l) {
    float eL0 = __shfl(vs[2], l - 1, 64);
    float eL1 = __shfl(vs[3], l - 1, 64);
    float eR0 = __shfl(vs[0], l + 1, 64);
    float eR1 = __shfl(vs[1], l + 1, 64);
    if (l == 0)  { eL0 = 0.f; eL1 = 0.f; }
    if (l == 63) { eR0 = 0.f; eR1 = 0.f; }
    float m = vs[1] + vs[2];
    float core = vs[0] + m;          // vs0+vs1+vs2
    float c2 = m + vs[3];            // vs1+vs2+vs3
    S[0] = core + eL0 + eL1;
    S[1] = core + vs[3] + eL1;
    S[2] = core + vs[3] + eR0;
    S[3] = c2 + eR0 + eR1;
}

__device__ __forceinline__ void hwin_i(const int* vs, int* S, int l) {
    int eL0 = __shfl(vs[2], l - 1, 64);
    int eL1 = __shfl(vs[3], l - 1, 64);
    int eR0 = __shfl(vs[0], l + 1, 64);
    int eR1 = __shfl(vs[1], l + 1, 64);
    if (l == 0)  { eL0 = 0; eL1 = 0; }
    if (l == 63) { eR0 = 0; eR1 = 0; }
    int m = vs[1] + vs[2];
    int core = vs[0] + m;
    int c2 = m + vs[3];
    S[0] = core + eL0 + eL1;
    S[1] = core + vs[3] + eL1;
    S[2] = core + vs[3] + eR0;
    S[3] = c2 + eR0 + eR1;
}

// ---------------- kernel 2: the heavy pass (also computes global counts on chunk==0) ----
// grid = B * NTILES * NCHUNKS = 4*16*32 = 2048 blocks, 256 threads.
// wave w: output rows R0+4w..R0+4w+3; lane l: cols 4l..4l+3 (full 256-wide row per wave).
__global__ __launch_bounds__(256) void k_loss(const float* __restrict__ F,
                                              const unsigned char* __restrict__ code,
                                              double* __restrict__ lsum,
                                              unsigned int* __restrict__ cnts) {
    __shared__ unsigned int csh[TR*64];   // code tile, 20 rows x 256 bytes
    __shared__ float red[8];
    const int t = threadIdx.x, w = t >> 6, l = t & 63;
    const int bx = blockIdx.x;
    const int chunk = bx & (NCHUNKS - 1);
    const int tile = (bx >> 5) & (NTILES - 1);
    const int b = bx >> 9;
    const int R0 = tile * TH;

    // ---- stage code tile; out-of-image rows get lab=2 (contributes nothing) ----
    for (int idx = t; idx < TR*64; idx += 256) {
        int rr = idx >> 6, grow = R0 - 2 + rr;
        unsigned int v = 0x02020202u;
        if ((unsigned)grow < HH) v = ((const unsigned int*)code)[(b*HH + grow)*64 + (idx & 63)];
        csh[idx] = v;
    }
    __syncthreads();

    const int rbase = R0 + 4*w - 2;   // wave's first input row (global)

    // ---- per-thread mask build for its 8 input rows x 4 cols ----
    unsigned int cw[8];
    #pragma unroll
    for (int rr = 0; rr < 8; rr++) cw[rr] = csh[(4*w + rr)*64 + l];

    float fm0[8][4], fm1[8][4];       // 0/1 floats: (lab==c)&good per (row,col)
    unsigned int mgd[8], mcls[8];     // bit masks: good-class (bits0-3 c0, 4-7 c1), class
    #pragma unroll
    for (int rr = 0; rr < 8; rr++) {
        unsigned int u = cw[rr], mg = 0, mc = 0;
        #pragma unroll
        for (int j = 0; j < 4; j++) {
            unsigned int q = (u >> (8*j)) & 255u;
            unsigned int lab2 = q & 3u, good = (q >> 2) & 1u;
            unsigned int c0 = (lab2 == 0u) ? 1u : 0u;
            unsigned int c1 = (lab2 == 1u) ? 1u : 0u;
            mg |= (c0 & good) << j;
            mg |= (c1 & good) << (4 + j);
            mc |= c0 << j;
            mc |= c1 << (4 + j);
            fm0[rr][j] = (float)(c0 & good);
            fm1[rr][j] = (float)(c1 & good);
        }
        mgd[rr] = mg; mcls[rr] = mc;
    }

    // ---- counts / wq precompute (channel-invariant) ----
    float wq[16];
    unsigned int mse0bits = 0, mse1bits = 0, labbits = 0;
    int ccal0 = 0, ccal1 = 0, cms0 = 0, cms1 = 0;
    #pragma unroll
    for (int o = 0; o < 4; o++) {
        int vg0[4] = {0,0,0,0}, vg1[4] = {0,0,0,0}, vc0[4] = {0,0,0,0}, vc1[4] = {0,0,0,0};
        #pragma unroll
        for (int k = 0; k < 5; k++) {
            unsigned int mg = mgd[o+k], mc = mcls[o+k];
            #pragma unroll
            for (int j = 0; j < 4; j++) {
                vg0[j] += (mg >> j) & 1;  vg1[j] += (mg >> (4+j)) & 1;
                vc0[j] += (mc >> j) & 1;  vc1[j] += (mc >> (4+j)) & 1;
            }
        }
        int bg0[4], bg1[4], bc0[4], bc1[4];
        hwin_i(vg0, bg0, l); hwin_i(vg1, bg1, l);
        hwin_i(vc0, bc0, l); hwin_i(vc1, bc1, l);
        #pragma unroll
        for (int j = 0; j < 4; j++) {
            unsigned int q = (cw[o+2] >> (8*j)) & 255u;
            int lab2 = q & 3, good = (q >> 2) & 1, edge = (q >> 3) & 1;
            int bcl = (lab2 == 1) ? bc1[j] : bc0[j];
            int bgl = (lab2 == 1) ? bg1[j] : bg0[j];
            int ccls = bcl - 1;          // ring class count (center counts itself in box)
            int ccorr = bgl - good;      // ring corr count
            int isc = (lab2 < 2) && edge;
            int cal = isc && (ccls >= 1);
            int mse = isc && good && (ccorr >= 1);
            int idx = o*4 + j;
            wq[idx] = mse ? (1.0f / ((float)ccorr + 1e-5f)) : 0.0f;
            labbits  |= ((unsigned)(lab2 & 1)) << idx;
            mse0bits |= ((unsigned)(mse & (lab2 == 0))) << idx;
            mse1bits |= ((unsigned)(mse & (lab2 == 1))) << idx;
            ccal0 += cal & (lab2 == 0);  ccal1 += cal & (lab2 == 1);
            cms0  += mse & (lab2 == 0);  cms1  += mse & (lab2 == 1);
        }
    }

    // global cal/mse counts: only chunk==0 blocks contribute (each pixel once)
    if (chunk == 0) {
        for (int off = 32; off > 0; off >>= 1) {
            ccal0 += __shfl_down(ccal0, off, 64);
            ccal1 += __shfl_down(ccal1, off, 64);
            cms0  += __shfl_down(cms0,  off, 64);
            cms1  += __shfl_down(cms1,  off, 64);
        }
        if (l == 0) {
            atomicAdd(&cnts[0], (unsigned)ccal0);
            atomicAdd(&cnts[1], (unsigned)ccal1);
            atomicAdd(&cnts[2], (unsigned)cms0);
            atomicAdd(&cnts[3], (unsigned)cms1);
        }
    }

    // ---- channel loop: global-direct float4 loads, register vertical, shuffle horizontal ----
    unsigned int rowok = 0;
    #pragma unroll
    for (int rr = 0; rr < 8; rr++)
        if ((unsigned)(rbase + rr) < HH) rowok |= 1u << rr;

    const float4* fb = (const float4*)F + (((size_t)(b*CC + chunk*NCH)) << 14);  // 16384 float4/plane
    float acc0 = 0.f, acc1 = 0.f;

    #pragma unroll 1
    for (int c = 0; c < NCH; c++) {
        const float4* pl = fb + ((size_t)c << 14);
        float4 ring[5];
        #pragma unroll
        for (int rr = 0; rr < 8; rr++) {
            float4 v = make_float4(0.f, 0.f, 0.f, 0.f);
            if (rowok & (1u << rr)) v = pl[(rbase + rr)*64 + l];  // wave-uniform branch
            ring[rr % 5] = v;
            if (rr >= 4) {
                const int o = rr - 4;
                float vs0[4] = {0.f,0.f,0.f,0.f}, vs1[4] = {0.f,0.f,0.f,0.f};
                #pragma unroll
                for (int k = 0; k < 5; k++) {
                    const int row = o + k;
                    const float4 rv = ring[row % 5];
                    #pragma unroll
                    for (int j = 0; j < 4; j++) {
                        float x = f4get(rv, j);
                        vs0[j] = fmaf(fm0[row][j], x, vs0[j]);
                        vs1[j] = fmaf(fm1[row][j], x, vs1[j]);
                    }
                }
                float S0[4], S1[4];
                hwin_f(vs0, S0, l);
                hwin_f(vs1, S1, l);
                const float4 ctr = ring[(o + 2) % 5];
                #pragma unroll
                for (int j = 0; j < 4; j++) {
                    const int idx = o*4 + j;
                    float fc = f4get(ctr, j);
                    float Ssel = ((labbits >> idx) & 1u) ? S1[j] : S0[j];
                    float S = Ssel - fc;                 // ring sum (center good=1 at mse px)
                    float d = fmaf(-S, wq[idx], fc);     // fc - S/(ccorr+eps)
                    float dd = d * d;
                    acc0 += ((mse0bits >> idx) & 1u) ? dd : 0.f;
                    acc1 += ((mse1bits >> idx) & 1u) ? dd : 0.f;
                }
            }
        }
    }

    // ---- reduce: wave shuffle -> LDS -> double atomics ----
    for (int off = 32; off > 0; off >>= 1) {
        acc0 += __shfl_down(acc0, off, 64);
        acc1 += __shfl_down(acc1, off, 64);
    }
    if (l == 0) { red[w*2] = acc0; red[w*2 + 1] = acc1; }
    __syncthreads();
    if (t == 0) {
        float a0 = red[0] + red[2] + red[4] + red[6];
        float a1 = red[1] + red[3] + red[5] + red[7];
        atomicAdd(&lsum[0], (double)a0);
        atomicAdd(&lsum[1], (double)a1);
    }
}

// ---------------- kernel 3: finalize scalar ----------------
__global__ void k_final(const double* __restrict__ lsum,
                        const unsigned int* __restrict__ cnts, float* out) {
    if (threadIdx.x == 0 && blockIdx.x == 0) {
        float total = 0.f, ncls = 0.f;
        for (int c = 0; c < 2; c++) {
            double num = lsum[c];
            unsigned int calc = cnts[c], msec = cnts[2 + c];
            float denom = fmaxf((float)msec * (float)CC, 1.0f);
            float lc = (float)(num / (double)denom);
            if (calc >= 1u && msec >= 1u) { total += lc; ncls += 1.f; }
        }
        out[0] = (ncls == 0.f) ? total : total / fmaxf(ncls, 1.f);
    }
}

extern "C" void kernel_launch(void* const* d_in, const int* in_sizes, int n_in,
                              void* d_out, int out_size, void* d_ws, size_t ws_size,
                              hipStream_t stream) {
    const float* feats = (const float*)d_in[0];        // [4,256,256,256] fp32
    const float* cls   = (const float*)d_in[1];        // [4,2,256,256] fp32
    const int*   gt    = (const int*)d_in[2];          // [4,256,256] int32
    double* lsum = (double*)d_ws;                      // [0,16)
    unsigned int* cnts = (unsigned int*)((char*)d_ws + 16);  // [16,32)
    unsigned char* code = (unsigned char*)d_ws + 64;   // B*H*W bytes
    float* out = (float*)d_out;

    const int npix = BB*HH*WW;
    k_init<<<1, 64, 0, stream>>>((unsigned int*)d_ws);
    k_code<<<npix/256, 256, 0, stream>>>(cls, gt, code);
    k_loss<<<BB*NTILES*NCHUNKS, 256, 0, stream>>>(feats, code, lsum, cnts);
    k_final<<<1, 64, 0, stream>>>(lsum, cnts, out);
}